// Round 1
// baseline (725.787 us; speedup 1.0000x reference)
//
#include <hip/hip_runtime.h>
#include <math.h>

#define IS3 0.57735026918962576f   // 1/sqrt(3)
#define IS6 0.40824829046386302f   // 1/sqrt(6)

__device__ __forceinline__ float fastrcp(float x) { return __builtin_amdgcn_rcpf(x); }

// tanh(x) = 1 - 2/(exp(2x)+1). Saturates correctly at +/-1 for |x| large
// (exp underflow -> -1, overflow/inf -> +1). Uses v_exp_f32 + v_rcp_f32.
__device__ __forceinline__ float ftanh(float x) {
    float e = __expf(2.0f * x);
    return 1.0f - 2.0f * fastrcp(e + 1.0f);
}

__device__ __forceinline__ float Tnl(float x, float w1, float w2) {
    return ftanh(w2 * ftanh(w1 * x));
}

// One thread per edge. Computes the 4 UNIQUE message components
// (msg[1]==msg[0], msg[5:8]==msg[2:5] by connection symmetry) and
// atomically accumulates: agg4[t] = {scalarSum, vx, vy, vz}, dsum, cnt.
__global__ __launch_bounds__(256) void edge_kernel(
    const int* __restrict__ ei, const float* __restrict__ f,
    const float* __restrict__ d, const float* __restrict__ a,
    const float* __restrict__ w1p, const float* __restrict__ w2p,
    float* __restrict__ agg4, float* __restrict__ dsum, float* __restrict__ cnt,
    int E)
{
    int e = blockIdx.x * 256 + threadIdx.x;
    if (e >= E) return;
    int s = ei[e];
    int t = ei[E + e];
    float w10 = w1p[0], w11 = w1p[1], w20 = w2p[0], w21 = w2p[1];

    const float4* f4 = (const float4*)f;
    float4 sA = f4[2*s], sB = f4[2*s+1];
    float4 tA = f4[2*t], tB = f4[2*t+1];
    float de = d[e];
    float4 av = ((const float4*)a)[e];
    float a0 = av.x, ax = av.y, ay = av.z, az = av.w;

    // h scalars (l=0 slots): f_src[0], f_src[1], f_tgt[0], f_tgt[1], d
    float sc[5] = { sA.x, sA.y, tA.x, tA.y, de };
    // h vectors (l=1 slots): f_src[2:5], f_src[5:8], f_tgt[2:5], f_tgt[5:8]
    float vx[4] = { sA.z, sB.y, tA.z, tB.y };
    float vy[4] = { sA.w, sB.z, tA.w, tB.z };
    float vz[4] = { sB.x, sB.w, tB.x, tB.w };

    float mS = 0.f, mX = 0.f, mY = 0.f, mZ = 0.f;
    #pragma unroll
    for (int i = 0; i < 5; ++i) {
        // (0,0,0): scalar h * a_l0 -> scalar out
        mS += Tnl(sc[i] * a0, w10, w20);
        // (0,1,1): scalar h * a_l1 / sqrt3 -> vector out
        mX += Tnl(sc[i] * ax * IS3, w11, w21);
        mY += Tnl(sc[i] * ay * IS3, w11, w21);
        mZ += Tnl(sc[i] * az * IS3, w11, w21);
    }
    #pragma unroll
    for (int i = 0; i < 4; ++i) {
        // (1,1,0): dot(v, a_l1)/sqrt3 -> scalar out
        float dva = vx[i]*ax + vy[i]*ay + vz[i]*az;
        mS += Tnl(dva * IS3, w11, w21);
        // (1,0,1): v * a_l0 / sqrt3 -> vector out
        mX += Tnl(vx[i] * a0 * IS3, w10, w20);
        mY += Tnl(vy[i] * a0 * IS3, w10, w20);
        mZ += Tnl(vz[i] * a0 * IS3, w10, w20);
        // (1,1,1): cross(v, a_l1)/sqrt6 -> vector out
        float cx = vy[i]*az - vz[i]*ay;
        float cy = vz[i]*ax - vx[i]*az;
        float cz = vx[i]*ay - vy[i]*ax;
        mX += Tnl(cx * IS6, w11, w21);
        mY += Tnl(cy * IS6, w11, w21);
        mZ += Tnl(cz * IS6, w11, w21);
    }

    float* base = agg4 + (size_t)4*t;
    atomicAdd(base + 0, mS);
    atomicAdd(base + 1, mX);
    atomicAdd(base + 2, mY);
    atomicAdd(base + 3, mZ);
    atomicAdd(dsum + t, de);
    atomicAdd(cnt + t, 1.0f);
}

// One thread per node: invariants -> MLP (weights in LDS, wave-uniform
// broadcast reads) -> sigmoid gates -> out = f + gate_full * agg.
__global__ __launch_bounds__(256) void node_kernel(
    const float* __restrict__ f, const float* __restrict__ agg4,
    const float* __restrict__ dsum, const float* __restrict__ cnt,
    const float* __restrict__ W0, const float* __restrict__ b0,
    const float* __restrict__ W1, const float* __restrict__ b1,
    const float* __restrict__ W2, const float* __restrict__ b2,
    float* __restrict__ out, int N)
{
    __shared__ float sW0[9*64];
    __shared__ float sb0[64];
    __shared__ float sW1[64*32];
    __shared__ float sb1[32];
    __shared__ float sW2[32*4];
    __shared__ float sb2[4];
    for (int i = threadIdx.x; i < 9*64;  i += 256) sW0[i] = W0[i];
    for (int i = threadIdx.x; i < 64;    i += 256) sb0[i] = b0[i];
    for (int i = threadIdx.x; i < 64*32; i += 256) sW1[i] = W1[i];
    for (int i = threadIdx.x; i < 32;    i += 256) sb1[i] = b1[i];
    for (int i = threadIdx.x; i < 32*4;  i += 256) sW2[i] = W2[i];
    for (int i = threadIdx.x; i < 4;     i += 256) sb2[i] = b2[i];
    __syncthreads();

    int n = blockIdx.x * 256 + threadIdx.x;
    if (n >= N) return;

    float4 fA = ((const float4*)f)[2*n];
    float4 fB = ((const float4*)f)[2*n+1];
    float aS = agg4[4*n+0], ax = agg4[4*n+1], ay = agg4[4*n+2], az = agg4[4*n+3];

    float psi[9];
    psi[0] = fA.x; psi[1] = fA.y;
    psi[2] = sqrtf(fA.z*fA.z + fA.w*fA.w + fB.x*fB.x);
    psi[3] = sqrtf(fB.y*fB.y + fB.z*fB.z + fB.w*fB.w);
    psi[4] = aS; psi[5] = aS;
    float nv = sqrtf(ax*ax + ay*ay + az*az);
    psi[6] = nv; psi[7] = nv;
    psi[8] = dsum[n] * fastrcp(cnt[n] + 1e-8f);

    float x0[64];
    #pragma unroll 4
    for (int j = 0; j < 64; ++j) {
        float acc = sb0[j];
        #pragma unroll
        for (int i = 0; i < 9; ++i) acc += psi[i] * sW0[i*64 + j];
        x0[j] = fmaxf(acc, 0.f);
    }
    float x1[32];
    #pragma unroll 4
    for (int j = 0; j < 32; ++j) {
        float acc = sb1[j];
        #pragma unroll 8
        for (int i = 0; i < 64; ++i) acc += x0[i] * sW1[i*32 + j];
        x1[j] = fmaxf(acc, 0.f);
    }
    float g[4];
    #pragma unroll
    for (int j = 0; j < 4; ++j) {
        float acc = sb2[j];
        #pragma unroll
        for (int i = 0; i < 32; ++i) acc += x1[i] * sW2[i*4 + j];
        g[j] = fastrcp(1.0f + __expf(-acc));   // sigmoid
    }

    float* o = out + (size_t)8*n;
    o[0] = fA.x + g[0]*aS;
    o[1] = fA.y + g[1]*aS;
    o[2] = fA.z + g[2]*ax;
    o[3] = fA.w + g[2]*ay;
    o[4] = fB.x + g[2]*az;
    o[5] = fB.y + g[3]*ax;
    o[6] = fB.z + g[3]*ay;
    o[7] = fB.w + g[3]*az;
}

extern "C" void kernel_launch(void* const* d_in, const int* in_sizes, int n_in,
                              void* d_out, int out_size, void* d_ws, size_t ws_size,
                              hipStream_t stream) {
    const int*   ei = (const int*)d_in[0];
    const float* f  = (const float*)d_in[1];
    const float* d  = (const float*)d_in[2];
    const float* a  = (const float*)d_in[3];
    const float* w1 = (const float*)d_in[4];
    const float* w2 = (const float*)d_in[5];
    const float* W0 = (const float*)d_in[6];
    const float* b0 = (const float*)d_in[7];
    const float* W1 = (const float*)d_in[8];
    const float* b1 = (const float*)d_in[9];
    const float* W2 = (const float*)d_in[10];
    const float* b2 = (const float*)d_in[11];
    int E = in_sizes[0] / 2;
    int N = in_sizes[1] / 8;

    float* ws   = (float*)d_ws;
    float* agg4 = ws;                    // N*4
    float* dsum = ws + (size_t)4 * N;    // N
    float* cnt  = ws + (size_t)5 * N;    // N

    hipMemsetAsync(d_ws, 0, (size_t)6 * N * sizeof(float), stream);

    edge_kernel<<<dim3((E + 255) / 256), dim3(256), 0, stream>>>(
        ei, f, d, a, w1, w2, agg4, dsum, cnt, E);

    node_kernel<<<dim3((N + 255) / 256), dim3(256), 0, stream>>>(
        f, agg4, dsum, cnt, W0, b0, W1, b1, W2, b2, (float*)d_out, N);
}

// Round 2
// 709.049 us; speedup vs baseline: 1.0236x; 1.0236x over previous
//
#include <hip/hip_runtime.h>
#include <math.h>

#define IS3 0.57735026918962576f   // 1/sqrt(3)
#define IS6 0.40824829046386302f   // 1/sqrt(6)

__device__ __forceinline__ float fastrcp(float x) { return __builtin_amdgcn_rcpf(x); }

// tanh(x) = 1 - 2/(exp(2x)+1). Saturates correctly at +/-1.
__device__ __forceinline__ float ftanh(float x) {
    float e = __expf(2.0f * x);
    return 1.0f - 2.0f * fastrcp(e + 1.0f);
}

__device__ __forceinline__ float Tnl(float x, float w1, float w2) {
    return ftanh(w2 * ftanh(w1 * x));
}

// One thread per edge. 4 unique message components (msg[1]==msg[0],
// msg[5:8]==msg[2:5] by connection symmetry). Per-node accumulator record:
// agg8[8*t + {0..5}] = {mS, mX, mY, mZ, dsum, cnt} -- 6 floats in ONE 64B
// line, accumulated with fire-and-forget global_atomic_add_f32.
__global__ __launch_bounds__(256) void edge_kernel(
    const int* __restrict__ ei, const float* __restrict__ f,
    const float* __restrict__ d, const float* __restrict__ a,
    const float* __restrict__ w1p, const float* __restrict__ w2p,
    float* __restrict__ agg8, int E)
{
    int e = blockIdx.x * 256 + threadIdx.x;
    if (e >= E) return;
    int s = ei[e];
    int t = ei[E + e];
    float w10 = w1p[0], w11 = w1p[1], w20 = w2p[0], w21 = w2p[1];

    const float4* f4 = (const float4*)f;
    float4 sA = f4[2*s], sB = f4[2*s+1];
    float4 tA = f4[2*t], tB = f4[2*t+1];
    float de = d[e];
    float4 av = ((const float4*)a)[e];
    float a0 = av.x, ax = av.y, ay = av.z, az = av.w;

    float sc[5] = { sA.x, sA.y, tA.x, tA.y, de };
    float vx[4] = { sA.z, sB.y, tA.z, tB.y };
    float vy[4] = { sA.w, sB.z, tA.w, tB.z };
    float vz[4] = { sB.x, sB.w, tB.x, tB.w };

    float mS = 0.f, mX = 0.f, mY = 0.f, mZ = 0.f;
    #pragma unroll
    for (int i = 0; i < 5; ++i) {
        mS += Tnl(sc[i] * a0, w10, w20);
        mX += Tnl(sc[i] * ax * IS3, w11, w21);
        mY += Tnl(sc[i] * ay * IS3, w11, w21);
        mZ += Tnl(sc[i] * az * IS3, w11, w21);
    }
    #pragma unroll
    for (int i = 0; i < 4; ++i) {
        float dva = vx[i]*ax + vy[i]*ay + vz[i]*az;
        mS += Tnl(dva * IS3, w11, w21);
        mX += Tnl(vx[i] * a0 * IS3, w10, w20);
        mY += Tnl(vy[i] * a0 * IS3, w10, w20);
        mZ += Tnl(vz[i] * a0 * IS3, w10, w20);
        float cx = vy[i]*az - vz[i]*ay;
        float cy = vz[i]*ax - vx[i]*az;
        float cz = vx[i]*ay - vy[i]*ax;
        mX += Tnl(cx * IS6, w11, w21);
        mY += Tnl(cy * IS6, w11, w21);
        mZ += Tnl(cz * IS6, w11, w21);
    }

    float* base = agg8 + (size_t)8*t;
    unsafeAtomicAdd(base + 0, mS);
    unsafeAtomicAdd(base + 1, mX);
    unsafeAtomicAdd(base + 2, mY);
    unsafeAtomicAdd(base + 3, mZ);
    unsafeAtomicAdd(base + 4, de);
    unsafeAtomicAdd(base + 5, 1.0f);
}

// One thread per node: invariants -> MLP (weights in LDS) -> gates -> out.
__global__ __launch_bounds__(256) void node_kernel(
    const float* __restrict__ f, const float* __restrict__ agg8,
    const float* __restrict__ W0, const float* __restrict__ b0,
    const float* __restrict__ W1, const float* __restrict__ b1,
    const float* __restrict__ W2, const float* __restrict__ b2,
    float* __restrict__ out, int N)
{
    __shared__ float sW0[9*64];
    __shared__ float sb0[64];
    __shared__ float sW1[64*32];
    __shared__ float sb1[32];
    __shared__ float sW2[32*4];
    __shared__ float sb2[4];
    for (int i = threadIdx.x; i < 9*64;  i += 256) sW0[i] = W0[i];
    for (int i = threadIdx.x; i < 64;    i += 256) sb0[i] = b0[i];
    for (int i = threadIdx.x; i < 64*32; i += 256) sW1[i] = W1[i];
    for (int i = threadIdx.x; i < 32;    i += 256) sb1[i] = b1[i];
    for (int i = threadIdx.x; i < 32*4;  i += 256) sW2[i] = W2[i];
    for (int i = threadIdx.x; i < 4;     i += 256) sb2[i] = b2[i];
    __syncthreads();

    int n = blockIdx.x * 256 + threadIdx.x;
    if (n >= N) return;

    float4 fA = ((const float4*)f)[2*n];
    float4 fB = ((const float4*)f)[2*n+1];
    float4 gA = ((const float4*)agg8)[2*n];
    float4 gB = ((const float4*)agg8)[2*n+1];
    float aS = gA.x, ax = gA.y, ay = gA.z, az = gA.w;

    float psi[9];
    psi[0] = fA.x; psi[1] = fA.y;
    psi[2] = sqrtf(fA.z*fA.z + fA.w*fA.w + fB.x*fB.x);
    psi[3] = sqrtf(fB.y*fB.y + fB.z*fB.z + fB.w*fB.w);
    psi[4] = aS; psi[5] = aS;
    float nv = sqrtf(ax*ax + ay*ay + az*az);
    psi[6] = nv; psi[7] = nv;
    psi[8] = gB.x * fastrcp(gB.y + 1e-8f);   // dsum / (cnt + eps)

    float x0[64];
    #pragma unroll 4
    for (int j = 0; j < 64; ++j) {
        float acc = sb0[j];
        #pragma unroll
        for (int i = 0; i < 9; ++i) acc += psi[i] * sW0[i*64 + j];
        x0[j] = fmaxf(acc, 0.f);
    }
    float x1[32];
    #pragma unroll 4
    for (int j = 0; j < 32; ++j) {
        float acc = sb1[j];
        #pragma unroll 8
        for (int i = 0; i < 64; ++i) acc += x0[i] * sW1[i*32 + j];
        x1[j] = fmaxf(acc, 0.f);
    }
    float g[4];
    #pragma unroll
    for (int j = 0; j < 4; ++j) {
        float acc = sb2[j];
        #pragma unroll
        for (int i = 0; i < 32; ++i) acc += x1[i] * sW2[i*4 + j];
        g[j] = fastrcp(1.0f + __expf(-acc));   // sigmoid
    }

    float* o = out + (size_t)8*n;
    o[0] = fA.x + g[0]*aS;
    o[1] = fA.y + g[1]*aS;
    o[2] = fA.z + g[2]*ax;
    o[3] = fA.w + g[2]*ay;
    o[4] = fB.x + g[2]*az;
    o[5] = fB.y + g[3]*ax;
    o[6] = fB.z + g[3]*ay;
    o[7] = fB.w + g[3]*az;
}

extern "C" void kernel_launch(void* const* d_in, const int* in_sizes, int n_in,
                              void* d_out, int out_size, void* d_ws, size_t ws_size,
                              hipStream_t stream) {
    const int*   ei = (const int*)d_in[0];
    const float* f  = (const float*)d_in[1];
    const float* d  = (const float*)d_in[2];
    const float* a  = (const float*)d_in[3];
    const float* w1 = (const float*)d_in[4];
    const float* w2 = (const float*)d_in[5];
    const float* W0 = (const float*)d_in[6];
    const float* b0 = (const float*)d_in[7];
    const float* W1 = (const float*)d_in[8];
    const float* b1 = (const float*)d_in[9];
    const float* W2 = (const float*)d_in[10];
    const float* b2 = (const float*)d_in[11];
    int E = in_sizes[0] / 2;
    int N = in_sizes[1] / 8;

    float* agg8 = (float*)d_ws;   // N * 8 floats: {mS,mX,mY,mZ,dsum,cnt,pad,pad}

    hipMemsetAsync(d_ws, 0, (size_t)8 * N * sizeof(float), stream);

    edge_kernel<<<dim3((E + 255) / 256), dim3(256), 0, stream>>>(
        ei, f, d, a, w1, w2, agg8, E);

    node_kernel<<<dim3((N + 255) / 256), dim3(256), 0, stream>>>(
        f, agg8, W0, b0, W1, b1, W2, b2, (float*)d_out, N);
}

// Round 3
// 289.845 us; speedup vs baseline: 2.5041x; 2.4463x over previous
//
#include <hip/hip_runtime.h>
#include <math.h>

#define IS3 0.57735026918962576f   // 1/sqrt(3)
#define IS6 0.40824829046386302f   // 1/sqrt(6)

__device__ __forceinline__ float fastrcp(float x) { return __builtin_amdgcn_rcpf(x); }

// tanh(x) = 1 - 2/(exp(2x)+1). Saturates correctly at +/-1.
__device__ __forceinline__ float ftanh(float x) {
    float e = __expf(2.0f * x);
    return 1.0f - 2.0f * fastrcp(e + 1.0f);
}

__device__ __forceinline__ float Tnl(float x, float w1, float w2) {
    return ftanh(w2 * ftanh(w1 * x));
}

// ---- K1: one returning int atomic per edge -> rank within target + histogram
__global__ __launch_bounds__(256) void rank_kernel(
    const int* __restrict__ ei, unsigned* __restrict__ cnt,
    unsigned* __restrict__ rank, int E)
{
    int e = blockIdx.x * 256 + threadIdx.x;
    if (e >= E) return;
    int t = ei[E + e];
    rank[e] = atomicAdd(&cnt[t], 1u);
}

// ---- S1: per-block sums of cnt
__global__ __launch_bounds__(256) void scan1_kernel(
    const unsigned* __restrict__ cnt, unsigned* __restrict__ bsum, int N)
{
    __shared__ unsigned s[256];
    int i = blockIdx.x * 256 + threadIdx.x;
    unsigned v = (i < N) ? cnt[i] : 0u;
    s[threadIdx.x] = v;
    __syncthreads();
    for (int o = 128; o > 0; o >>= 1) {
        if (threadIdx.x < o) s[threadIdx.x] += s[threadIdx.x + o];
        __syncthreads();
    }
    if (threadIdx.x == 0) bsum[blockIdx.x] = s[0];
}

// ---- S2: single-block exclusive scan of block sums (NB <= 1024)
__global__ __launch_bounds__(1024) void scan2_kernel(
    const unsigned* __restrict__ bsum, unsigned* __restrict__ bpre, int NB)
{
    __shared__ unsigned s[1024];
    unsigned v = (threadIdx.x < (unsigned)NB) ? bsum[threadIdx.x] : 0u;
    s[threadIdx.x] = v;
    for (int o = 1; o < 1024; o <<= 1) {
        __syncthreads();
        unsigned u = (threadIdx.x >= (unsigned)o) ? s[threadIdx.x - o] : 0u;
        __syncthreads();
        s[threadIdx.x] += u;
    }
    __syncthreads();
    if (threadIdx.x < (unsigned)NB) bpre[threadIdx.x] = s[threadIdx.x] - v;
}

// ---- S3: per-block exclusive scan of cnt + block prefix -> off
__global__ __launch_bounds__(256) void scan3_kernel(
    const unsigned* __restrict__ cnt, const unsigned* __restrict__ bpre,
    unsigned* __restrict__ off, int N)
{
    __shared__ unsigned s[256];
    int i = blockIdx.x * 256 + threadIdx.x;
    unsigned v = (i < N) ? cnt[i] : 0u;
    s[threadIdx.x] = v;
    for (int o = 1; o < 256; o <<= 1) {
        __syncthreads();
        unsigned u = (threadIdx.x >= (unsigned)o) ? s[threadIdx.x - o] : 0u;
        __syncthreads();
        s[threadIdx.x] += u;
    }
    __syncthreads();
    if (i < N) off[i] = bpre[blockIdx.x] + s[threadIdx.x] - v;
}

// ---- K3: compute 4 unique message components, scatter to CSR slot (no atomics)
__global__ __launch_bounds__(256) void msg_kernel(
    const int* __restrict__ ei, const float* __restrict__ f,
    const float* __restrict__ d, const float* __restrict__ a,
    const float* __restrict__ w1p, const float* __restrict__ w2p,
    const unsigned* __restrict__ off, const unsigned* __restrict__ rank,
    float4* __restrict__ msg4, float* __restrict__ dq, int E)
{
    int e = blockIdx.x * 256 + threadIdx.x;
    if (e >= E) return;
    int s = ei[e];
    int t = ei[E + e];
    float w10 = w1p[0], w11 = w1p[1], w20 = w2p[0], w21 = w2p[1];

    const float4* f4 = (const float4*)f;
    float4 sA = f4[2*s], sB = f4[2*s+1];
    float4 tA = f4[2*t], tB = f4[2*t+1];
    float de = d[e];
    float4 av = ((const float4*)a)[e];
    float a0 = av.x, ax = av.y, ay = av.z, az = av.w;

    float sc[5] = { sA.x, sA.y, tA.x, tA.y, de };
    float vx[4] = { sA.z, sB.y, tA.z, tB.y };
    float vy[4] = { sA.w, sB.z, tA.w, tB.z };
    float vz[4] = { sB.x, sB.w, tB.x, tB.w };

    float mS = 0.f, mX = 0.f, mY = 0.f, mZ = 0.f;
    #pragma unroll
    for (int i = 0; i < 5; ++i) {
        mS += Tnl(sc[i] * a0, w10, w20);
        mX += Tnl(sc[i] * ax * IS3, w11, w21);
        mY += Tnl(sc[i] * ay * IS3, w11, w21);
        mZ += Tnl(sc[i] * az * IS3, w11, w21);
    }
    #pragma unroll
    for (int i = 0; i < 4; ++i) {
        float dva = vx[i]*ax + vy[i]*ay + vz[i]*az;
        mS += Tnl(dva * IS3, w11, w21);
        mX += Tnl(vx[i] * a0 * IS3, w10, w20);
        mY += Tnl(vy[i] * a0 * IS3, w10, w20);
        mZ += Tnl(vz[i] * a0 * IS3, w10, w20);
        float cx = vy[i]*az - vz[i]*ay;
        float cy = vz[i]*ax - vx[i]*az;
        float cz = vx[i]*ay - vy[i]*ax;
        mX += Tnl(cx * IS6, w11, w21);
        mY += Tnl(cy * IS6, w11, w21);
        mZ += Tnl(cz * IS6, w11, w21);
    }

    unsigned q = off[t] + rank[e];
    msg4[q] = make_float4(mS, mX, mY, mZ);
    dq[q] = de;
}

// ---- K4: per-node segment sum (no atomics) + invariants + MLP + gates + out.
// MLP fully unrolled, interleaved so no runtime-indexed private arrays
// (the R1/R2 node kernel spilled x0[64]/x1[32] to scratch: ~200us).
__global__ __launch_bounds__(256) void node_kernel(
    const float* __restrict__ f, const float4* __restrict__ msg4,
    const float* __restrict__ dq, const unsigned* __restrict__ off,
    const float* __restrict__ W0, const float* __restrict__ b0,
    const float* __restrict__ W1, const float* __restrict__ b1,
    const float* __restrict__ W2, const float* __restrict__ b2,
    float* __restrict__ out, int N, int E)
{
    __shared__ float sW0[9*64];
    __shared__ float sb0[64];
    __shared__ float sW1[64*32];
    __shared__ float sb1[32];
    __shared__ float sW2[32*4];
    __shared__ float sb2[4];
    for (int i = threadIdx.x; i < 9*64;  i += 256) sW0[i] = W0[i];
    for (int i = threadIdx.x; i < 64;    i += 256) sb0[i] = b0[i];
    for (int i = threadIdx.x; i < 64*32; i += 256) sW1[i] = W1[i];
    for (int i = threadIdx.x; i < 32;    i += 256) sb1[i] = b1[i];
    for (int i = threadIdx.x; i < 32*4;  i += 256) sW2[i] = W2[i];
    for (int i = threadIdx.x; i < 4;     i += 256) sb2[i] = b2[i];
    __syncthreads();

    int n = blockIdx.x * 256 + threadIdx.x;
    if (n >= N) return;

    unsigned start = off[n];
    unsigned end = (n == N - 1) ? (unsigned)E : off[n + 1];

    float aS = 0.f, ax = 0.f, ay = 0.f, az = 0.f, ds = 0.f;
    for (unsigned q = start; q < end; ++q) {
        float4 m = msg4[q];
        aS += m.x; ax += m.y; ay += m.z; az += m.w;
        ds += dq[q];
    }
    float cntf = (float)(end - start);

    float4 fA = ((const float4*)f)[2*n];
    float4 fB = ((const float4*)f)[2*n+1];

    float psi[9];
    psi[0] = fA.x; psi[1] = fA.y;
    psi[2] = sqrtf(fA.z*fA.z + fA.w*fA.w + fB.x*fB.x);
    psi[3] = sqrtf(fB.y*fB.y + fB.z*fB.z + fB.w*fB.w);
    psi[4] = aS; psi[5] = aS;
    float nv = sqrtf(ax*ax + ay*ay + az*az);
    psi[6] = nv; psi[7] = nv;
    psi[8] = ds * fastrcp(cntf + 1e-8f);

    // layer1+layer2 interleaved: x0_i folded into x1 immediately
    float x1[32];
    #pragma unroll
    for (int j = 0; j < 32; ++j) x1[j] = sb1[j];
    #pragma unroll
    for (int i = 0; i < 64; ++i) {
        float acc = sb0[i];
        #pragma unroll
        for (int k = 0; k < 9; ++k) acc += psi[k] * sW0[k*64 + i];
        acc = fmaxf(acc, 0.f);
        #pragma unroll
        for (int j = 0; j < 32; ++j) x1[j] += acc * sW1[i*32 + j];
    }
    #pragma unroll
    for (int j = 0; j < 32; ++j) x1[j] = fmaxf(x1[j], 0.f);

    float g[4];
    #pragma unroll
    for (int j = 0; j < 4; ++j) {
        float acc = sb2[j];
        #pragma unroll
        for (int i = 0; i < 32; ++i) acc += x1[i] * sW2[i*4 + j];
        g[j] = fastrcp(1.0f + __expf(-acc));   // sigmoid
    }

    float* o = out + (size_t)8*n;
    o[0] = fA.x + g[0]*aS;
    o[1] = fA.y + g[1]*aS;
    o[2] = fA.z + g[2]*ax;
    o[3] = fA.w + g[2]*ay;
    o[4] = fB.x + g[2]*az;
    o[5] = fB.y + g[3]*ax;
    o[6] = fB.z + g[3]*ay;
    o[7] = fB.w + g[3]*az;
}

extern "C" void kernel_launch(void* const* d_in, const int* in_sizes, int n_in,
                              void* d_out, int out_size, void* d_ws, size_t ws_size,
                              hipStream_t stream) {
    const int*   ei = (const int*)d_in[0];
    const float* f  = (const float*)d_in[1];
    const float* d  = (const float*)d_in[2];
    const float* a  = (const float*)d_in[3];
    const float* w1 = (const float*)d_in[4];
    const float* w2 = (const float*)d_in[5];
    const float* W0 = (const float*)d_in[6];
    const float* b0 = (const float*)d_in[7];
    const float* W1 = (const float*)d_in[8];
    const float* b1 = (const float*)d_in[9];
    const float* W2 = (const float*)d_in[10];
    const float* b2 = (const float*)d_in[11];
    int E = in_sizes[0] / 2;
    int N = in_sizes[1] / 8;

    // workspace layout (bytes):
    //   msg4 : E*16        @ 0
    //   dq   : E*4         @ E*16
    //   rank : E*4         @ E*20
    //   cnt  : N*4         @ E*24
    //   off  : N*4         @ E*24 + N*4
    //   bsum : 1024*4      @ E*24 + N*8
    //   bpre : 1024*4      @ E*24 + N*8 + 4096
    char* w = (char*)d_ws;
    float4*   msg4 = (float4*)w;
    float*    dq   = (float*)(w + (size_t)E * 16);
    unsigned* rank = (unsigned*)(w + (size_t)E * 20);
    unsigned* cnt  = (unsigned*)(w + (size_t)E * 24);
    unsigned* off  = (unsigned*)(w + (size_t)E * 24 + (size_t)N * 4);
    unsigned* bsum = (unsigned*)(w + (size_t)E * 24 + (size_t)N * 8);
    unsigned* bpre = bsum + 1024;

    int NB = (N + 255) / 256;           // 391 for N=100000 (<=1024 required)
    int EB = (E + 255) / 256;

    hipMemsetAsync(cnt, 0, (size_t)N * sizeof(unsigned), stream);

    rank_kernel <<<dim3(EB), dim3(256), 0, stream>>>(ei, cnt, rank, E);
    scan1_kernel<<<dim3(NB), dim3(256), 0, stream>>>(cnt, bsum, N);
    scan2_kernel<<<dim3(1), dim3(1024), 0, stream>>>(bsum, bpre, NB);
    scan3_kernel<<<dim3(NB), dim3(256), 0, stream>>>(cnt, bpre, off, N);
    msg_kernel  <<<dim3(EB), dim3(256), 0, stream>>>(ei, f, d, a, w1, w2,
                                                     off, rank, msg4, dq, E);
    node_kernel <<<dim3(NB), dim3(256), 0, stream>>>(f, msg4, dq, off,
                                                     W0, b0, W1, b1, W2, b2,
                                                     (float*)d_out, N, E);
}